// Round 1
// baseline (1027.522 us; speedup 1.0000x reference)
//
#include <hip/hip_runtime.h>
#include <hip/hip_bf16.h>
#include <hip/hip_cooperative_groups.h>

namespace cg = cooperative_groups;

// Problem constants (fixed by reference setup_inputs)
#define S_ROWS 4096
#define Q_ROWS 8192
#define DIM 256
#define N_SEL 19      // selection iterations (20 scan steps, last one only produces scores)
#define COLSPLIT 8    // phase-B column splits (4096/8 = 512 cols per block)
#define CBLOCKS 128   // cooperative kernel blocks
#define CROWS 64      // query rows per cooperative block (8192/128)

// Workspace layout (in floats)
#define WS_INV_Q 0
#define WS_QQ    (WS_INV_Q + Q_ROWS)
#define WS_INV_S (WS_QQ + Q_ROWS)
#define WS_PP    (WS_INV_S + S_ROWS)
#define WS_TOP3  (WS_PP + S_ROWS)                   // [Q_ROWS][4]
#define WS_TOP3P (WS_TOP3 + Q_ROWS * 4)             // [COLSPLIT][Q_ROWS][4]
#define WS_KTH   (WS_TOP3P + COLSPLIT * Q_ROWS * 4) // unsigned [32]
#define WS_CNT   (WS_KTH + 32)                      // int [32]
#define WS_LISTS (WS_CNT + 32)                      // int [N_SEL * Q_ROWS]

// ---------------------------------------------------------------------------
// Row L2-norms: inv[r] = 1/||x_r||, ssq[r] = sum((x_r * inv)^2)  (matches ref's
// explicit sum(qf*qf) which is ~1 but not exactly 1 in fp32)
__global__ void norm_rows(const float* __restrict__ x, float* __restrict__ inv,
                          float* __restrict__ ssq, int nrows) {
    int w = (blockIdx.x * blockDim.x + threadIdx.x) >> 6;
    int lane = threadIdx.x & 63;
    if (w >= nrows) return;
    float4 v = reinterpret_cast<const float4*>(x + (size_t)w * DIM)[lane];
    float s = v.x * v.x + v.y * v.y + v.z * v.z + v.w * v.w;
#pragma unroll
    for (int o = 1; o < 64; o <<= 1) s += __shfl_xor(s, o, 64);
    float invn = 1.0f / sqrtf(s);
    float t = v.x * invn; float u = t * t;
    t = v.y * invn; u += t * t;
    t = v.z * invn; u += t * t;
    t = v.w * invn; u += t * t;
#pragma unroll
    for (int o = 1; o < 64; o <<= 1) u += __shfl_xor(u, o, 64);
    if (lane == 0) { inv[w] = invn; ssq[w] = u; }
}

// ---------------------------------------------------------------------------
// Init per-call mutable state (kth/cnt) and the "ones" second output.
__global__ void init_ws(unsigned* __restrict__ kth, int* __restrict__ cnt,
                        float* __restrict__ out, int n_extra) {
    int t = blockIdx.x * blockDim.x + threadIdx.x;
    if (t < 32) { kth[t] = 0x7F800000u; cnt[t] = 0; }
    if (t < n_extra) out[Q_ROWS + t] = 1.0f;
}

// ---------------------------------------------------------------------------
// Phase B: fused fp32 GEMM (qf_norm . sf_norm^T) + per-row top-3 of
// dist = sqrt(max(qq + pp - 2*dot, 1e-12)). Grid: 64 rowblocks x COLSPLIT.
__launch_bounds__(256, 2)
__global__ void knn_support_kernel(const float* __restrict__ qf, const float* __restrict__ sf,
                                   const float* __restrict__ inv_q, const float* __restrict__ inv_s,
                                   const float* __restrict__ qq, const float* __restrict__ pp,
                                   float* __restrict__ top3part) {
    __shared__ __align__(16) float smem[2 * 128 * 36];
    float (*As)[36] = reinterpret_cast<float(*)[36]>(smem);
    float (*Bs)[36] = reinterpret_cast<float(*)[36]>(smem + 128 * 36);

    int bid = blockIdx.x;
    int rb = (bid & 63) * 128;   // row block base
    int cs = bid >> 6;           // column split 0..7
    int tid = threadIdx.x;
    int tx = tid & 15, ty = tid >> 4;

    float t3[8][3];
#pragma unroll
    for (int i = 0; i < 8; ++i) t3[i][0] = t3[i][1] = t3[i][2] = INFINITY;

    for (int ch = 0; ch < 4; ++ch) {
        int cb = cs * 512 + ch * 128;
        float acc[8][8];
#pragma unroll
        for (int i = 0; i < 8; ++i)
#pragma unroll
            for (int j = 0; j < 8; ++j) acc[i][j] = 0.0f;

        for (int kt = 0; kt < 8; ++kt) {
#pragma unroll
            for (int q = 0; q < 4; ++q) {
                int idx = q * 256 + tid;      // 0..1023 element-of-tile (in float4 units per row: 8)
                int row = idx >> 3, f4 = idx & 7;
                float4 a = *reinterpret_cast<const float4*>(qf + (size_t)(rb + row) * DIM + kt * 32 + f4 * 4);
                float sa = inv_q[rb + row];
                As[row][f4 * 4 + 0] = a.x * sa; As[row][f4 * 4 + 1] = a.y * sa;
                As[row][f4 * 4 + 2] = a.z * sa; As[row][f4 * 4 + 3] = a.w * sa;
                float4 b = *reinterpret_cast<const float4*>(sf + (size_t)(cb + row) * DIM + kt * 32 + f4 * 4);
                float sb = inv_s[cb + row];
                Bs[row][f4 * 4 + 0] = b.x * sb; Bs[row][f4 * 4 + 1] = b.y * sb;
                Bs[row][f4 * 4 + 2] = b.z * sb; Bs[row][f4 * 4 + 3] = b.w * sb;
            }
            __syncthreads();
#pragma unroll
            for (int kk = 0; kk < 32; kk += 4) {
                float4 av[8], bv[8];
#pragma unroll
                for (int i = 0; i < 8; ++i) av[i] = *reinterpret_cast<const float4*>(&As[ty + 16 * i][kk]);
#pragma unroll
                for (int j = 0; j < 8; ++j) bv[j] = *reinterpret_cast<const float4*>(&Bs[tx + 16 * j][kk]);
#pragma unroll
                for (int i = 0; i < 8; ++i)
#pragma unroll
                    for (int j = 0; j < 8; ++j) {
                        acc[i][j] += av[i].x * bv[j].x;
                        acc[i][j] += av[i].y * bv[j].y;
                        acc[i][j] += av[i].z * bv[j].z;
                        acc[i][j] += av[i].w * bv[j].w;
                    }
            }
            __syncthreads();
        }
        // epilogue: distances + top-3 update
#pragma unroll
        for (int i = 0; i < 8; ++i) {
            float qqr = qq[rb + ty + 16 * i];
#pragma unroll
            for (int j = 0; j < 8; ++j) {
                float d2 = qqr + pp[cb + tx + 16 * j] - 2.0f * acc[i][j];
                float d = sqrtf(fmaxf(d2, 1e-12f));
                float mx = fmaxf(fmaxf(t3[i][0], t3[i][1]), t3[i][2]);
                if (d < mx) {
                    if (t3[i][0] == mx) t3[i][0] = d;
                    else if (t3[i][1] == mx) t3[i][1] = d;
                    else t3[i][2] = d;
                }
            }
        }
        __syncthreads();
    }

    // merge per-row top3 across the 16 tx lanes
#pragma unroll
    for (int i = 0; i < 8; ++i) {
        int row = ty + 16 * i;
        smem[(row * 16 + tx) * 3 + 0] = t3[i][0];
        smem[(row * 16 + tx) * 3 + 1] = t3[i][1];
        smem[(row * 16 + tx) * 3 + 2] = t3[i][2];
    }
    __syncthreads();
    if (tid < 128) {
        float b0 = INFINITY, b1 = INFINITY, b2 = INFINITY;
        for (int t = 0; t < 48; ++t) {
            float d = smem[tid * 48 + t];
            float mx = fmaxf(fmaxf(b0, b1), b2);
            if (d < mx) {
                if (b0 == mx) b0 = d;
                else if (b1 == mx) b1 = d;
                else b2 = d;
            }
        }
        float* dst = top3part + ((size_t)cs * Q_ROWS + rb + tid) * 4;
        dst[0] = b0; dst[1] = b1; dst[2] = b2; dst[3] = 0.0f;
    }
}

// ---------------------------------------------------------------------------
// Merge the COLSPLIT partial top-3s into one top-3 per row.
__global__ void merge_top3(const float* __restrict__ top3part, float* __restrict__ top3) {
    int row = blockIdx.x * blockDim.x + threadIdx.x;
    if (row >= Q_ROWS) return;
    float b0 = INFINITY, b1 = INFINITY, b2 = INFINITY;
#pragma unroll
    for (int cs = 0; cs < COLSPLIT; ++cs) {
        const float* p = top3part + ((size_t)cs * Q_ROWS + row) * 4;
#pragma unroll
        for (int k = 0; k < 3; ++k) {
            float d = p[k];
            float mx = fmaxf(fmaxf(b0, b1), b2);
            if (d < mx) {
                if (b0 == mx) b0 = d;
                else if (b1 == mx) b1 = d;
                else b2 = d;
            }
        }
    }
    float* dst = top3 + (size_t)row * 4;
    dst[0] = b0; dst[1] = b1; dst[2] = b2; dst[3] = 0.0f;
}

// ---------------------------------------------------------------------------
// Phase C: 19 cooperative selection iterations + final score write.
// Each block owns CROWS=64 query rows; their normalized features live in LDS.
__global__ void iterate_select(const float* __restrict__ qf, const float* __restrict__ inv_q,
                               const float* __restrict__ qq,
                               float* __restrict__ top3, unsigned* __restrict__ kth_bits,
                               int* __restrict__ cnt, int* __restrict__ lists,
                               float* __restrict__ out) {
    cg::grid_group grid = cg::this_grid();
    __shared__ __align__(16) float qfr[CROWS][DIM];   // 64 KB: block's rows, pre-normalized
    __shared__ float t3s[CROWS][3];
    __shared__ float qfc[DIM];
    __shared__ int knowns[CROWS];
    __shared__ float scoresh[CROWS];

    int tid = threadIdx.x;
    int rbase = blockIdx.x * CROWS;
    int lane = tid & 63;
    int wv = tid >> 6;

    // stage this block's rows (pre-scaled by inv norm)
#pragma unroll
    for (int q = 0; q < 16; ++q) {
        int idx = q * 256 + tid;    // float4 index, 64 per row
        int row = idx >> 6, f4 = idx & 63;
        float4 v = reinterpret_cast<const float4*>(qf + (size_t)(rbase + row) * DIM)[f4];
        float s = inv_q[rbase + row];
        reinterpret_cast<float4*>(&qfr[row][0])[f4] = make_float4(v.x * s, v.y * s, v.z * s, v.w * s);
    }
    if (tid < CROWS) {
        const float* p = top3 + (size_t)(rbase + tid) * 4;
        t3s[tid][0] = p[0]; t3s[tid][1] = p[1]; t3s[tid][2] = p[2];
        knowns[tid] = 0;
    }
    __syncthreads();

    for (int t = 0; t < N_SEL; ++t) {
        // 1: per-row scores, block-min over unknown, global atomicMin
        if (wv == 0) {
            float sc = (t3s[lane][0] + t3s[lane][1] + t3s[lane][2]) * (1.0f / 3.0f);
            scoresh[lane] = sc;
            float mn = knowns[lane] ? INFINITY : sc;
#pragma unroll
            for (int o = 1; o < 64; o <<= 1) mn = fminf(mn, __shfl_xor(mn, o, 64));
            if (lane == 0) atomicMin(&kth_bits[t], __float_as_uint(mn));
        }
        grid.sync();
        // 2: rows with score <= kth (ties included) become known; append to list
        if (wv == 0) {
            float kth = __uint_as_float(
                __hip_atomic_load(&kth_bits[t], __ATOMIC_RELAXED, __HIP_MEMORY_SCOPE_AGENT));
            if (!knowns[lane] && scoresh[lane] <= kth) {
                int pos = atomicAdd(&cnt[t], 1);
                __hip_atomic_store(&lists[t * Q_ROWS + pos], rbase + lane,
                                   __ATOMIC_RELAXED, __HIP_MEMORY_SCOPE_AGENT);
                knowns[lane] = 1;
            }
        }
        grid.sync();
        // 3: update every owned row's top-3 with distances to each new column
        int m = __hip_atomic_load(&cnt[t], __ATOMIC_RELAXED, __HIP_MEMORY_SCOPE_AGENT);
        for (int jj = 0; jj < m; ++jj) {
            int c = __hip_atomic_load(&lists[t * Q_ROWS + jj], __ATOMIC_RELAXED,
                                      __HIP_MEMORY_SCOPE_AGENT);
            qfc[tid] = qf[(size_t)c * DIM + tid] * inv_q[c];
            __syncthreads();
            float qqc = qq[c];
            for (int rr = 0; rr < 16; ++rr) {
                int row = wv * 16 + rr;
                float4 v = reinterpret_cast<const float4*>(&qfr[row][0])[lane];
                float4 w4 = reinterpret_cast<const float4*>(qfc)[lane];
                float d = v.x * w4.x + v.y * w4.y + v.z * w4.z + v.w * w4.w;
#pragma unroll
                for (int o = 1; o < 64; o <<= 1) d += __shfl_xor(d, o, 64);
                if (lane == 0) {
                    float d2 = qq[rbase + row] + qqc - 2.0f * d;
                    float dist = sqrtf(fmaxf(d2, 1e-12f));
                    float mx = fmaxf(fmaxf(t3s[row][0], t3s[row][1]), t3s[row][2]);
                    if (dist < mx) {
                        if (t3s[row][0] == mx) t3s[row][0] = dist;
                        else if (t3s[row][1] == mx) t3s[row][1] = dist;
                        else t3s[row][2] = dist;
                    }
                }
            }
            __syncthreads();
        }
        __syncthreads();
    }

    // final scores -> output (1 - score)
    if (wv == 0) {
        float sc = (t3s[lane][0] + t3s[lane][1] + t3s[lane][2]) * (1.0f / 3.0f);
        out[rbase + lane] = 1.0f - sc;
    }
}

// ---------------------------------------------------------------------------
extern "C" void kernel_launch(void* const* d_in, const int* in_sizes, int n_in,
                              void* d_out, int out_size, void* d_ws, size_t ws_size,
                              hipStream_t stream) {
    const float* sfeat = (const float*)d_in[0];
    const float* qfeat = (const float*)d_in[2];
    float* out = (float*)d_out;

    float* ws = (float*)d_ws;
    float* inv_q = ws + WS_INV_Q;
    float* qq    = ws + WS_QQ;
    float* inv_s = ws + WS_INV_S;
    float* pp    = ws + WS_PP;
    float* top3  = ws + WS_TOP3;
    float* top3p = ws + WS_TOP3P;
    unsigned* kth = (unsigned*)(ws + WS_KTH);
    int* cnt   = (int*)(ws + WS_CNT);
    int* lists = (int*)(ws + WS_LISTS);

    int n_extra = out_size - Q_ROWS;
    if (n_extra < 0) n_extra = 0;

    norm_rows<<<Q_ROWS * 64 / 256, 256, 0, stream>>>(qfeat, inv_q, qq, Q_ROWS);
    norm_rows<<<S_ROWS * 64 / 256, 256, 0, stream>>>(sfeat, inv_s, pp, S_ROWS);
    init_ws<<<32, 256, 0, stream>>>(kth, cnt, out, n_extra);
    knn_support_kernel<<<64 * COLSPLIT, 256, 0, stream>>>(qfeat, sfeat, inv_q, inv_s, qq, pp, top3p);
    merge_top3<<<Q_ROWS / 256, 256, 0, stream>>>(top3p, top3);

    const float* a0 = qfeat; const float* a1 = inv_q; const float* a2 = qq;
    float* a3 = top3; unsigned* a4 = kth; int* a5 = cnt; int* a6 = lists; float* a7 = out;
    void* cargs[] = {&a0, &a1, &a2, &a3, &a4, &a5, &a6, &a7};
    hipLaunchCooperativeKernel(iterate_select, dim3(CBLOCKS), dim3(256), cargs, 0, stream);
}